// Round 2
// baseline (592.892 us; speedup 1.0000x reference)
//
#include <hip/hip_runtime.h>
#include <hip/hip_bf16.h>

#define T_TOK 2048
#define H_DIM 2048
#define I_DIM 2048
#define E_NUM 8

#define BM  128
#define BK  64
#define BN1 64    // gemm1: per-matrix N tile (W1 | W3 stacked in one block)
#define BN2 128   // gemm2: N tile

typedef float  floatx4 __attribute__((ext_vector_type(4)));
typedef __bf16 bf16x8  __attribute__((ext_vector_type(8)));
typedef __bf16 bf16x4  __attribute__((ext_vector_type(4)));

// XOR-swizzled LDS granule address (16B granules, 8 per 128-byte logical row).
__device__ __forceinline__ int swz(int row, int g) {
    return (row * 8 + (g ^ ((row >> 1) & 7))) * 16;
}

// Direct global->LDS 16B DMA. LDS dest is wave-uniform base + lane*16 (linear);
// the swizzle is applied by pre-swizzling the per-lane GLOBAL source address
// (involution), so the swizzled read side stays unchanged.
typedef const __attribute__((address_space(1))) void* as1_cptr;
typedef __attribute__((address_space(3))) void*       as3_ptr;
__device__ __forceinline__ void glds16(const void* g, void* l) {
    __builtin_amdgcn_global_load_lds((as1_cptr)g, (as3_ptr)l, 16, 0, 0);
}

// ---------------------------------------------------------------------------
// Kernel 1: router — logits, top-2, renorm weights, per-expert lists,
//           PLUS fp32->bf16 conversion of hidden_states (it reads hs anyway).
// ---------------------------------------------------------------------------
__global__ __launch_bounds__(64) void router_kernel(
    const float* __restrict__ hs, const float* __restrict__ gate_w,
    int* __restrict__ counts, int* __restrict__ lists, float* __restrict__ wpair,
    __bf16* __restrict__ Xbf)
{
    const int t    = blockIdx.x;
    const int lane = threadIdx.x;

    float acc[E_NUM];
#pragma unroll
    for (int e = 0; e < E_NUM; e++) acc[e] = 0.f;

    const float4* hsrow = (const float4*)(hs + (size_t)t * H_DIM);
#pragma unroll
    for (int it = 0; it < (H_DIM / 4) / 64; it++) {
        const int c = lane + it * 64;
        const float4 x = hsrow[c];
        const bf16x4 v = {(__bf16)x.x, (__bf16)x.y, (__bf16)x.z, (__bf16)x.w};
        *(bf16x4*)(Xbf + (size_t)t * H_DIM + 4 * c) = v;
#pragma unroll
        for (int e = 0; e < E_NUM; e++) {
            const float4 w = ((const float4*)(gate_w + (size_t)e * H_DIM))[c];
            acc[e] += x.x * w.x + x.y * w.y + x.z * w.z + x.w * w.w;
        }
    }
#pragma unroll
    for (int e = 0; e < E_NUM; e++) {
        float v = acc[e];
        for (int off = 32; off >= 1; off >>= 1) v += __shfl_xor(v, off, 64);
        acc[e] = v;
    }
    if (lane == 0) {
        float l0 = -1e30f; int i0 = 0;
        for (int e = 0; e < E_NUM; e++) if (acc[e] > l0) { l0 = acc[e]; i0 = e; }
        float l1 = -1e30f; int i1 = (i0 == 0) ? 1 : 0;
        for (int e = 0; e < E_NUM; e++) if (e != i0 && acc[e] > l1) { l1 = acc[e]; i1 = e; }
        const float e1 = __expf(l1 - l0);
        const float s  = 1.f + e1;
        const int p0 = atomicAdd(&counts[i0], 1);
        lists[i0 * T_TOK + p0] = 2 * t;
        const int p1 = atomicAdd(&counts[i1], 1);
        lists[i1 * T_TOK + p1] = 2 * t + 1;
        wpair[2 * t]     = 1.f / s;
        wpair[2 * t + 1] = e1 / s;
    }
}

// ---------------------------------------------------------------------------
// Kernel 2: fused gate/up GEMM + SiLU.  A = silu(X@W1) * (X@W3), bf16 out.
// m97 structure: single-buffer LDS (32 KB), 2 barriers/K-iter, X via
// global_load_lds (16B, pre-swizzled source), W via float4 + reg transpose.
// Threads 0-127 stage W1, 128-255 stage W3.
// ---------------------------------------------------------------------------
__global__ __launch_bounds__(256, 3) void gemm1_kernel(
    const __bf16* __restrict__ Xbf, const float* __restrict__ w1,
    const float* __restrict__ w3, const int* __restrict__ counts,
    const int* __restrict__ lists, __bf16* __restrict__ Abuf)
{
    const int e   = blockIdx.z;
    const int n_e = counts[e];
    const int m0  = blockIdx.y * BM;
    if (m0 >= n_e) return;
    const int n0 = blockIdx.x * BN1;

    const int* list = lists + e * T_TOK;

    __shared__ __align__(16) __bf16 Xs [BM * BK];    // 16 KB
    __shared__ __align__(16) __bf16 B1s[BN1 * BK];   //  8 KB
    __shared__ __align__(16) __bf16 B3s[BN1 * BK];   //  8 KB

    const int tid  = threadIdx.x;
    const int wave = tid >> 6;
    const int lane = tid & 63;

    // ---- X DMA setup: instr i of wave w fills linear LDS granules
    //      L = (w*4+i)*64 + lane  ->  row = L>>3, pos = L&7.
    //      Source granule g = pos ^ ((row>>1)&7)  (swizzle involution).
    size_t xoff[4];
#pragma unroll
    for (int i = 0; i < 4; i++) {
        const int row = wave * 32 + i * 8 + (lane >> 3);
        const int r   = m0 + row;
        const int tok = (r < n_e) ? (list[r] >> 1) : 0;
        const int g   = (lane & 7) ^ ((4 * i + (lane >> 4)) & 7);
        xoff[i] = (size_t)tok * H_DIM + 8 * g;
    }

    // ---- W staging: per thread 8 rows x 4 cols (float4), transposed into
    //      4 K-granules. Wave-instr footprint: 4 rows x 256B, dense.
    const int half = tid >> 7;          // 0 = W1, 1 = W3
    const int t7   = tid & 127;
    const int wnp  = t7 & 15;           // col group: 4 cols at n0 + 4*wnp
    const int wkb  = t7 >> 4;           // k-granule 0..7
    const float* wsrc = (half ? w3 : w1) + (size_t)e * H_DIM * I_DIM
                      + (size_t)(8 * wkb) * I_DIM + n0 + 4 * wnp;
    __bf16* wdst = half ? B3s : B1s;

    const int wm   = (wave >> 1) * 64;  // 0 or 64
    const int wn   = (wave & 1) * 32;   // 0 or 32
    const int lrow = lane & 15;
    const int quad = lane >> 4;

    floatx4 accG[4][2], accU[4][2];
#pragma unroll
    for (int i = 0; i < 4; i++)
#pragma unroll
        for (int j = 0; j < 2; j++) {
            accG[i][j] = (floatx4){0.f, 0.f, 0.f, 0.f};
            accU[i][j] = (floatx4){0.f, 0.f, 0.f, 0.f};
        }

    for (int k0 = 0; k0 < H_DIM; k0 += BK) {
        // X tile -> LDS via DMA (4 x 1KB per wave, no VGPR round-trip)
#pragma unroll
        for (int i = 0; i < 4; i++)
            glds16(Xbf + xoff[i] + k0, Xs + (wave * 4 + i) * 512);
        // W tile: 8 x float4 (16B/lane), register transpose, 4 b128 writes
        {
            const float* s = wsrc + (size_t)k0 * I_DIM;
            floatx4 f[8];
#pragma unroll
            for (int j = 0; j < 8; j++) f[j] = *(const floatx4*)(s + (size_t)j * I_DIM);
#pragma unroll
            for (int c = 0; c < 4; c++) {
                bf16x8 gcol;
#pragma unroll
                for (int j = 0; j < 8; j++) gcol[j] = (__bf16)f[j][c];
                *(bf16x8*)((char*)wdst + swz(4 * wnp + c, wkb)) = gcol;
            }
        }
        __syncthreads();   // drains vmcnt(0): X DMA landed, W writes visible

#pragma unroll
        for (int s = 0; s < 2; s++) {
            bf16x8 af[4], b1f[2], b3f[2];
#pragma unroll
            for (int i = 0; i < 4; i++)
                af[i]  = *(const bf16x8*)((char*)Xs  + swz(wm + i * 16 + lrow, 4 * s + quad));
#pragma unroll
            for (int j = 0; j < 2; j++) {
                b1f[j] = *(const bf16x8*)((char*)B1s + swz(wn + j * 16 + lrow, 4 * s + quad));
                b3f[j] = *(const bf16x8*)((char*)B3s + swz(wn + j * 16 + lrow, 4 * s + quad));
            }
#pragma unroll
            for (int i = 0; i < 4; i++)
#pragma unroll
                for (int j = 0; j < 2; j++) {
                    accG[i][j] = __builtin_amdgcn_mfma_f32_16x16x32_bf16(af[i], b1f[j], accG[i][j], 0, 0, 0);
                    accU[i][j] = __builtin_amdgcn_mfma_f32_16x16x32_bf16(af[i], b3f[j], accU[i][j], 0, 0, 0);
                }
        }
        __syncthreads();   // all LDS reads done before next overwrite
    }

    // epilogue: silu(g)*u -> Abuf[p]  (C/D layout: col=lane&15, row=quad*4+reg)
#pragma unroll
    for (int i = 0; i < 4; i++) {
#pragma unroll
        for (int r = 0; r < 4; r++) {
            const int row = m0 + wm + i * 16 + quad * 4 + r;
            if (row < n_e) {
                const int p = list[row];
                __bf16* dst = Abuf + (size_t)p * I_DIM + n0 + wn + lrow;
#pragma unroll
                for (int j = 0; j < 2; j++) {
                    const float g = accG[i][j][r];
                    const float u = accU[i][j][r];
                    const float sv = g / (1.f + __expf(-g));
                    dst[j * 16] = (__bf16)(sv * u);
                }
            }
        }
    }
}

// ---------------------------------------------------------------------------
// Kernel 3: down-proj GEMM.  Y[p] = A[p] @ W2[e], bf16 out.  128x128 tile
// (m97 MFMA density), same staging scheme. Wave-tile 64x64 (2x2 wave grid).
// ---------------------------------------------------------------------------
__global__ __launch_bounds__(256, 3) void gemm2_kernel(
    const __bf16* __restrict__ Abuf, const float* __restrict__ w2,
    const int* __restrict__ counts, const int* __restrict__ lists,
    __bf16* __restrict__ Ybuf)
{
    const int e   = blockIdx.z;
    const int n_e = counts[e];
    const int m0  = blockIdx.y * BM;
    if (m0 >= n_e) return;
    const int n0 = blockIdx.x * BN2;

    const int*   list = lists + e * T_TOK;
    const float* w2e  = w2 + (size_t)e * I_DIM * H_DIM;

    __shared__ __align__(16) __bf16 As[BM * BK];     // 16 KB
    __shared__ __align__(16) __bf16 Bs[BN2 * BK];    // 16 KB (128 rows x 8 gran)

    const int tid  = threadIdx.x;
    const int wave = tid >> 6;
    const int lane = tid & 63;

    size_t aoff[4];
#pragma unroll
    for (int i = 0; i < 4; i++) {
        const int row = wave * 32 + i * 8 + (lane >> 3);
        const int r   = m0 + row;
        const int p   = (r < n_e) ? list[r] : 0;
        const int g   = (lane & 7) ^ ((4 * i + (lane >> 4)) & 7);
        aoff[i] = (size_t)p * I_DIM + 8 * g;
    }

    // W2 staging: 256 threads cover 128 cols x 8 k-granules, 4 granules each.
    const int np = tid & 31;            // col group: 4 cols at n0 + 4*np
    const int kb = tid >> 5;            // k-granule 0..7
    const float* wsrc = w2e + (size_t)(8 * kb) * H_DIM + n0 + 4 * np;

    const int wm   = (wave >> 1) * 64;
    const int wn   = (wave & 1) * 64;
    const int lrow = lane & 15;
    const int quad = lane >> 4;

    floatx4 acc[4][4];
#pragma unroll
    for (int i = 0; i < 4; i++)
#pragma unroll
        for (int j = 0; j < 4; j++) acc[i][j] = (floatx4){0.f, 0.f, 0.f, 0.f};

    for (int k0 = 0; k0 < I_DIM; k0 += BK) {
#pragma unroll
        for (int i = 0; i < 4; i++)
            glds16(Abuf + aoff[i] + k0, As + (wave * 4 + i) * 512);
        {
            const float* s = wsrc + (size_t)k0 * H_DIM;
            floatx4 f[8];
#pragma unroll
            for (int j = 0; j < 8; j++) f[j] = *(const floatx4*)(s + (size_t)j * H_DIM);
#pragma unroll
            for (int c = 0; c < 4; c++) {
                bf16x8 gcol;
#pragma unroll
                for (int j = 0; j < 8; j++) gcol[j] = (__bf16)f[j][c];
                *(bf16x8*)((char*)Bs + swz(4 * np + c, kb)) = gcol;
            }
        }
        __syncthreads();

#pragma unroll
        for (int s = 0; s < 2; s++) {
            bf16x8 af[4], bf[4];
#pragma unroll
            for (int i = 0; i < 4; i++)
                af[i] = *(const bf16x8*)((char*)As + swz(wm + i * 16 + lrow, 4 * s + quad));
#pragma unroll
            for (int j = 0; j < 4; j++)
                bf[j] = *(const bf16x8*)((char*)Bs + swz(wn + j * 16 + lrow, 4 * s + quad));
#pragma unroll
            for (int i = 0; i < 4; i++)
#pragma unroll
                for (int j = 0; j < 4; j++)
                    acc[i][j] = __builtin_amdgcn_mfma_f32_16x16x32_bf16(af[i], bf[j], acc[i][j], 0, 0, 0);
        }
        __syncthreads();
    }

#pragma unroll
    for (int i = 0; i < 4; i++) {
#pragma unroll
        for (int r = 0; r < 4; r++) {
            const int row = m0 + wm + i * 16 + quad * 4 + r;
            if (row < n_e) {
                const int p = list[row];
                __bf16* dst = Ybuf + (size_t)p * H_DIM + n0 + wn + lrow;
#pragma unroll
                for (int j = 0; j < 4; j++) dst[j * 16] = (__bf16)acc[i][j][r];
            }
        }
    }
}

// ---------------------------------------------------------------------------
// Kernel 4: combine.  out[t] = w[2t]*Y[2t] + w[2t+1]*Y[2t+1]  (fp32 out)
// ---------------------------------------------------------------------------
__global__ __launch_bounds__(256) void combine_kernel(
    const __bf16* __restrict__ Ybuf, const float* __restrict__ wpair,
    float* __restrict__ out)
{
    const int idx = blockIdx.x * 256 + threadIdx.x;
    const int t   = idx >> 9;
    const int hc  = (idx & 511) * 4;
    const float w0 = wpair[2 * t];
    const float w1 = wpair[2 * t + 1];
    const __bf16* y0 = Ybuf + (size_t)(2 * t) * H_DIM + hc;
    const __bf16* y1 = y0 + H_DIM;
    const bf16x4 a0 = *(const bf16x4*)y0;
    const bf16x4 a1 = *(const bf16x4*)y1;
    float4 o;
    o.x = w0 * (float)a0[0] + w1 * (float)a1[0];
    o.y = w0 * (float)a0[1] + w1 * (float)a1[1];
    o.z = w0 * (float)a0[2] + w1 * (float)a1[2];
    o.w = w0 * (float)a0[3] + w1 * (float)a1[3];
    *(float4*)(out + (size_t)t * H_DIM + hc) = o;
}

// ---------------------------------------------------------------------------
extern "C" void kernel_launch(void* const* d_in, const int* in_sizes, int n_in,
                              void* d_out, int out_size, void* d_ws, size_t ws_size,
                              hipStream_t stream)
{
    const float* hs     = (const float*)d_in[0];
    const float* gate_w = (const float*)d_in[1];
    const float* w1     = (const float*)d_in[2];
    const float* w3     = (const float*)d_in[3];
    const float* w2     = (const float*)d_in[4];
    float*       out    = (float*)d_out;

    char* ws = (char*)d_ws;
    int*    counts = (int*)(ws + 0);
    float*  wpair  = (float*)(ws + 1024);
    int*    lists  = (int*)(ws + 32768);
    // Xbf (8 MB, live: router->gemm1) and Ybuf (16.8 MB, live: gemm2->combine)
    // share the same region — lifetimes don't overlap.
    __bf16* Xbf    = (__bf16*)(ws + (1 << 17));
    __bf16* Ybuf   = (__bf16*)(ws + (1 << 17));
    __bf16* Abuf   = (__bf16*)(ws + (1 << 17) +
                               (size_t)2 * T_TOK * H_DIM * sizeof(__bf16));

    hipMemsetAsync(counts, 0, E_NUM * sizeof(int), stream);

    router_kernel<<<T_TOK, 64, 0, stream>>>(hs, gate_w, counts, lists, wpair, Xbf);

    gemm1_kernel<<<dim3(I_DIM / BN1, T_TOK / BM, E_NUM), 256, 0, stream>>>(
        Xbf, w1, w3, counts, lists, Abuf);

    gemm2_kernel<<<dim3(H_DIM / BN2, T_TOK / BM, E_NUM), 256, 0, stream>>>(
        Abuf, w2, counts, lists, Ybuf);

    combine_kernel<<<(T_TOK * H_DIM / 4) / 256, 256, 0, stream>>>(Ybuf, wpair, out);
}